// Round 10
// baseline (414.249 us; speedup 1.0000x reference)
//
#include <hip/hip_runtime.h>
#include <hip/hip_bf16.h>

#define NN 20000
#define EE 640000

typedef __attribute__((ext_vector_type(8))) short bf16x8;
typedef __attribute__((ext_vector_type(4))) float f32x4;

__device__ __forceinline__ ushort f2b(float f) {
    __hip_bfloat16 h = __float2bfloat16(f);
    return *(ushort*)&h;
}
__device__ __forceinline__ float b2f(ushort u) {
    __hip_bfloat16 h = *(__hip_bfloat16*)&u;
    return __bfloat162float(h);
}

// ---------------- CSR build ----------------

__global__ void init_cnt_kernel(int* __restrict__ cnt, int n) {
    int i = blockIdx.x * 256 + threadIdx.x;
    if (i < n) cnt[i] = 0;
}

__global__ void hist_kernel(const int* __restrict__ col, int* __restrict__ cnt, int e) {
    int i = blockIdx.x * 256 + threadIdx.x;
    if (i < e) atomicAdd(&cnt[col[i]], 1);
}

__global__ void dinv_kernel(const int* __restrict__ cnt, float* __restrict__ dinv, int n) {
    int i = blockIdx.x * 256 + threadIdx.x;
    if (i < n) dinv[i] = rsqrtf((float)(cnt[i] + 1));  // +1 self-loop; always > 0
}

__device__ __forceinline__ int block_exscan(int v) {
    __shared__ int wsum[4];
    int tid = threadIdx.x, lane = tid & 63, w = tid >> 6;
    int x = v;
    #pragma unroll
    for (int d = 1; d < 64; d <<= 1) {
        int y = __shfl_up(x, d, 64);
        if (lane >= d) x += y;
    }
    if (lane == 63) wsum[w] = x;
    __syncthreads();
    if (tid == 0) {
        int s = 0;
        #pragma unroll
        for (int k = 0; k < 4; ++k) { int t = wsum[k]; wsum[k] = s; s += t; }
    }
    __syncthreads();
    return wsum[w] + x - v;
}

__global__ __launch_bounds__(256) void scan_p1_kernel(const int* __restrict__ cnt,
                                                      int* __restrict__ offs,
                                                      int* __restrict__ bsum, int n) {
    int i = blockIdx.x * 256 + threadIdx.x;
    int v = (i < n) ? cnt[i] : 0;
    int e = block_exscan(v);
    if (i < n) offs[i] = e;
    if (threadIdx.x == 255) bsum[blockIdx.x] = e + v;
}

__global__ __launch_bounds__(256) void scan_p2_kernel(int* __restrict__ bsum, int nblk) {
    int t = threadIdx.x;
    int v = (t < nblk) ? bsum[t] : 0;
    int e = block_exscan(v);
    if (t < nblk) bsum[t] = e;
}

__global__ __launch_bounds__(256) void scan_p3_kernel(int* __restrict__ offs,
                                                      const int* __restrict__ bsum,
                                                      int* __restrict__ cursor, int n) {
    int i = blockIdx.x * 256 + threadIdx.x;
    if (i < n) {
        int o = offs[i] + bsum[blockIdx.x];
        offs[i] = o;
        cursor[i] = o;
    }
}

__global__ void scatter_kernel(const int* __restrict__ row, const int* __restrict__ col,
                               const float* __restrict__ dinv, int* __restrict__ cursor,
                               int2* __restrict__ pair, int e) {
    int i = blockIdx.x * 256 + threadIdx.x;
    if (i >= e) return;
    int s = row[i], d = col[i];
    int pos = atomicAdd(&cursor[d], 1);
    int2 p;
    p.x = s;
    p.y = __float_as_int(dinv[s] * dinv[d]);
    pair[pos] = p;
}

// ---------------- x f32 -> bf16 ----------------
__global__ __launch_bounds__(256) void cvt_kernel(const float* __restrict__ x,
                                                  ushort* __restrict__ xb, int total8) {
    int i = blockIdx.x * 256 + threadIdx.x;   // per 8 elements
    if (i >= total8) return;
    float4 a = ((const float4*)x)[2 * i];
    float4 b = ((const float4*)x)[2 * i + 1];
    union { bf16x8 v; ushort s[8]; } o;
    o.s[0] = f2b(a.x); o.s[1] = f2b(a.y); o.s[2] = f2b(a.z); o.s[3] = f2b(a.w);
    o.s[4] = f2b(b.x); o.s[5] = f2b(b.y); o.s[6] = f2b(b.z); o.s[7] = f2b(b.w);
    ((bf16x8*)xb)[i] = o.v;
}

// ---------------- weight prep: W [256][256] f32 -> Wt [256 col][768 kv] bf16 ----------------
__global__ __launch_bounds__(256) void wprep_kernel(const float* __restrict__ W,
                                                    ushort* __restrict__ Wt) {
    int col = blockIdx.x;
    for (int kv = threadIdx.x; kv < 768; kv += 256) {
        int k = kv & 255;
        float w = W[(size_t)k * 256 + col];
        ushort hi = f2b(w);
        ushort out = (kv < 256 || kv >= 512) ? hi : f2b(w - b2f(hi));
        Wt[(size_t)col * 768 + kv] = out;
    }
}

// ---------------- aggregation v8: fsub=16 x esub=4, truncation split ----------------
// hb bf16 [n][256]. chunk = bid&3 (64 feats, slice 2.56MB L2-fit). 4 waves = 4 nodes/block.
// Lane: esub = lane>>4 (4 edges in flight), fsub = lane&15 (bf16x4 within chunk).
// unroll 8 -> 32 edges in flight per wave. Output a2 [n][512] bf16 hi|lo.
__global__ __launch_bounds__(256) void agg_kernel(
    const ushort* __restrict__ hb,
    const int* __restrict__ offs, const int* __restrict__ cnt,
    const int2* __restrict__ pair,
    const float* __restrict__ dinv,
    ushort* __restrict__ a2, int n) {
    int chunk = blockIdx.x & 3;
    int node = (blockIdx.x >> 2) * 4 + (threadIdx.x >> 6);
    int lane = threadIdx.x & 63;
    int esub = lane >> 4, fsub = lane & 15;
    const ushort* base = hb + chunk * 64 + fsub * 4;
    const unsigned long long* pq = (const unsigned long long*)pair;

    int beg = offs[node], num = cnt[node];
    float a0 = 0.f, a1 = 0.f, av2 = 0.f, a3 = 0.f;

    int j = 0;
    for (; j + 32 <= num; j += 32) {          // full blocks: no predication
        #pragma unroll
        for (int u = 0; u < 8; ++u) {
            unsigned long long q = pq[beg + j + u * 4 + esub];
            float m = __int_as_float((int)(q >> 32));
            int s = (int)(q & 0xffffffffu);
            uint2 v = *(const uint2*)(base + (size_t)s * 256);
            a0  = fmaf(m, __uint_as_float(v.x << 16),          a0);
            a1  = fmaf(m, __uint_as_float(v.x & 0xffff0000u),  a1);
            av2 = fmaf(m, __uint_as_float(v.y << 16),          av2);
            a3  = fmaf(m, __uint_as_float(v.y & 0xffff0000u),  a3);
        }
    }
    if (j < num) {                             // one predicated tail block
        #pragma unroll
        for (int u = 0; u < 8; ++u) {
            int i = j + u * 4 + esub;
            bool p = i < num;
            unsigned long long q = pq[p ? beg + i : beg];
            float m = p ? __int_as_float((int)(q >> 32)) : 0.f;
            int s = (int)(q & 0xffffffffu);
            uint2 v = *(const uint2*)(base + (size_t)s * 256);
            a0  = fmaf(m, __uint_as_float(v.x << 16),          a0);
            a1  = fmaf(m, __uint_as_float(v.x & 0xffff0000u),  a1);
            av2 = fmaf(m, __uint_as_float(v.y << 16),          av2);
            a3  = fmaf(m, __uint_as_float(v.y & 0xffff0000u),  a3);
        }
    }

    // reduce across the 4 esub groups (2 butterfly steps)
    #pragma unroll
    for (int d = 16; d < 64; d <<= 1) {
        a0  += __shfl_xor(a0, d, 64);
        a1  += __shfl_xor(a1, d, 64);
        av2 += __shfl_xor(av2, d, 64);
        a3  += __shfl_xor(a3, d, 64);
    }

    if (esub == 0) {   // lanes 0..15 hold fsub 0..15
        float di = dinv[node];
        float sn = di * di;
        uint2 sv = *(const uint2*)(base + (size_t)node * 256);
        a0  = fmaf(sn, __uint_as_float(sv.x << 16),          a0);
        a1  = fmaf(sn, __uint_as_float(sv.x & 0xffff0000u),  a1);
        av2 = fmaf(sn, __uint_as_float(sv.y << 16),          av2);
        a3  = fmaf(sn, __uint_as_float(sv.y & 0xffff0000u),  a3);
        // truncation hi/lo split (hi = top 16 bits; lo = exact remainder, trunc to bf16)
        unsigned u0 = __float_as_uint(a0),  u1 = __float_as_uint(a1);
        unsigned u2 = __float_as_uint(av2), u3 = __float_as_uint(a3);
        float l0 = a0  - __uint_as_float(u0 & 0xffff0000u);
        float l1 = a1  - __uint_as_float(u1 & 0xffff0000u);
        float l2 = av2 - __uint_as_float(u2 & 0xffff0000u);
        float l3 = a3  - __uint_as_float(u3 & 0xffff0000u);
        ushort4 hi, lo;
        hi.x = (ushort)(u0 >> 16); hi.y = (ushort)(u1 >> 16);
        hi.z = (ushort)(u2 >> 16); hi.w = (ushort)(u3 >> 16);
        lo.x = (ushort)(__float_as_uint(l0) >> 16);
        lo.y = (ushort)(__float_as_uint(l1) >> 16);
        lo.z = (ushort)(__float_as_uint(l2) >> 16);
        lo.w = (ushort)(__float_as_uint(l3) >> 16);
        size_t off = (size_t)node * 512 + chunk * 64 + fsub * 4;
        *(ushort4*)(a2 + off)       = hi;
        *(ushort4*)(a2 + off + 256) = lo;
    }
}

// ---------------- LDS-free-loop MFMA GEMM, 4 waves K-split, 32x64 tile ----------------
// Block (cx, ry) computes C[ry*32 .. +32) x [cx*64 .. +64). Wave w handles K-steps
// w*6 .. w*6+5 (kv = step*32). Partials combined via padded LDS; wave 0 stores.
template<bool RELU, bool BF16OUT>
__global__ __launch_bounds__(256) void gemm_mfma_kernel(
    const ushort* __restrict__ A2, const ushort* __restrict__ Wt,
    const float* __restrict__ bias, void* __restrict__ Cout, int n) {
    __shared__ float red[3][64][36];   // +36 pad: 16B-aligned, ~8-way (cheap, once)
    int lane = threadIdx.x & 63;
    int wid = threadIdx.x >> 6;
    int rowbase = blockIdx.y * 32;
    int colbase = blockIdx.x * 64;
    int r = lane & 15;
    int q = lane >> 4;   // 0..3 -> 8-short k sub-chunk

    f32x4 zero = {0.f, 0.f, 0.f, 0.f};
    f32x4 acc[2][4];
    #pragma unroll
    for (int m = 0; m < 2; ++m)
        #pragma unroll
        for (int nn = 0; nn < 4; ++nn) acc[m][nn] = zero;

    const ushort* aptr0 = A2 + (size_t)(rowbase + r) * 512 + q * 8;
    const ushort* aptr1 = aptr0 + 16 * 512;
    const ushort* bbase = Wt + (size_t)(colbase + r) * 768 + q * 8;
    const ushort* bptr0 = bbase;
    const ushort* bptr1 = bbase + 16 * 768;
    const ushort* bptr2 = bbase + 32 * 768;
    const ushort* bptr3 = bbase + 48 * 768;

    bf16x8 a0A, a1A, b0A, b1A, b2A, b3A;
    bf16x8 a0B, a1B, b0B, b1B, b2B, b3B;

    auto ldfrag = [&](int s, bf16x8& A0, bf16x8& A1, bf16x8& B0, bf16x8& B1,
                      bf16x8& B2, bf16x8& B3) {
        int kv0 = s * 32;
        int acol = (kv0 < 256) ? kv0 : kv0 - 256;
        A0 = *(const bf16x8*)(aptr0 + acol);
        A1 = *(const bf16x8*)(aptr1 + acol);
        B0 = *(const bf16x8*)(bptr0 + kv0);
        B1 = *(const bf16x8*)(bptr1 + kv0);
        B2 = *(const bf16x8*)(bptr2 + kv0);
        B3 = *(const bf16x8*)(bptr3 + kv0);
    };
    auto domfma = [&](bf16x8& A0, bf16x8& A1, bf16x8& B0, bf16x8& B1,
                      bf16x8& B2, bf16x8& B3) {
        acc[0][0] = __builtin_amdgcn_mfma_f32_16x16x32_bf16(A0, B0, acc[0][0], 0, 0, 0);
        acc[0][1] = __builtin_amdgcn_mfma_f32_16x16x32_bf16(A0, B1, acc[0][1], 0, 0, 0);
        acc[0][2] = __builtin_amdgcn_mfma_f32_16x16x32_bf16(A0, B2, acc[0][2], 0, 0, 0);
        acc[0][3] = __builtin_amdgcn_mfma_f32_16x16x32_bf16(A0, B3, acc[0][3], 0, 0, 0);
        acc[1][0] = __builtin_amdgcn_mfma_f32_16x16x32_bf16(A1, B0, acc[1][0], 0, 0, 0);
        acc[1][1] = __builtin_amdgcn_mfma_f32_16x16x32_bf16(A1, B1, acc[1][1], 0, 0, 0);
        acc[1][2] = __builtin_amdgcn_mfma_f32_16x16x32_bf16(A1, B2, acc[1][2], 0, 0, 0);
        acc[1][3] = __builtin_amdgcn_mfma_f32_16x16x32_bf16(A1, B3, acc[1][3], 0, 0, 0);
    };

    int s0 = wid * 6;
    ldfrag(s0 + 0, a0A, a1A, b0A, b1A, b2A, b3A);
    #pragma unroll
    for (int s = 0; s < 6; s += 2) {
        ldfrag(s0 + s + 1, a0B, a1B, b0B, b1B, b2B, b3B);
        domfma(a0A, a1A, b0A, b1A, b2A, b3A);
        if (s + 2 < 6) ldfrag(s0 + s + 2, a0A, a1A, b0A, b1A, b2A, b3A);
        domfma(a0B, a1B, b0B, b1B, b2B, b3B);
    }

    if (wid != 0) {
        float* dst = &red[wid - 1][lane][0];
        #pragma unroll
        for (int m = 0; m < 2; ++m)
            #pragma unroll
            for (int nn = 0; nn < 4; ++nn)
                *(f32x4*)(dst + (m * 4 + nn) * 4) = acc[m][nn];
    }
    __syncthreads();
    if (wid == 0) {
        #pragma unroll
        for (int k = 0; k < 3; ++k) {
            const float* src = &red[k][lane][0];
            #pragma unroll
            for (int m = 0; m < 2; ++m)
                #pragma unroll
                for (int nn = 0; nn < 4; ++nn)
                    acc[m][nn] += *(const f32x4*)(src + (m * 4 + nn) * 4);
        }
        #pragma unroll
        for (int nn = 0; nn < 4; ++nn) {
            int col = colbase + nn * 16 + r;
            float bv = bias[col];
            #pragma unroll
            for (int m = 0; m < 2; ++m) {
                int grow0 = rowbase + m * 16 + q * 4;
                f32x4 v = acc[m][nn];
                #pragma unroll
                for (int rr = 0; rr < 4; ++rr) {
                    int row = grow0 + rr;
                    float val = v[rr] + bv;
                    if (RELU) val = fmaxf(val, 0.f);
                    if (BF16OUT)
                        ((ushort*)Cout)[(size_t)row * 256 + col] = f2b(val);
                    else
                        ((float*)Cout)[(size_t)row * 256 + col] = val;
                }
            }
        }
    }
}

// ---------------- final projection: out[i] = h3[i,:] . Wout + bout ----------------
__global__ __launch_bounds__(256) void out_kernel(
    const float* __restrict__ h3, const float* __restrict__ Wout,
    const float* __restrict__ bout, float* __restrict__ out, int n) {
    int node = blockIdx.x * 4 + (threadIdx.x >> 6);
    int lane = threadIdx.x & 63;
    if (node >= n) return;
    float4 v = ((const float4*)(h3 + (size_t)node * 256))[lane];
    float4 w = ((const float4*)Wout)[lane];
    float sum = v.x * w.x + v.y * w.y + v.z * w.z + v.w * w.w;
    #pragma unroll
    for (int d = 32; d > 0; d >>= 1) sum += __shfl_down(sum, d, 64);
    if (lane == 0) out[node] = sum + bout[0];
}

extern "C" void kernel_launch(void* const* d_in, const int* in_sizes, int n_in,
                              void* d_out, int out_size, void* d_ws, size_t ws_size,
                              hipStream_t stream) {
    const int n = NN, e = EE;
    const float* x    = (const float*)d_in[0];
    const int*   eidx = (const int*)d_in[1];
    const float* W1   = (const float*)d_in[2];
    const float* b1   = (const float*)d_in[3];
    const float* Wh   = (const float*)d_in[4];
    const float* bh   = (const float*)d_in[5];
    const float* W2   = (const float*)d_in[6];
    const float* b2   = (const float*)d_in[7];
    const float* Wout = (const float*)d_in[8];
    const float* bout = (const float*)d_in[9];
    const int* row = eidx;        // sources
    const int* col = eidx + e;    // destinations

    char* ws = (char*)d_ws;
    int*    cnt     = (int*)ws;    ws += (size_t)n * 4;
    int*    offs    = (int*)ws;    ws += (size_t)n * 4;
    int*    cursor  = (int*)ws;    ws += (size_t)n * 4;
    float*  dinv    = (float*)ws;  ws += (size_t)n * 4;
    int*    bsum    = (int*)ws;    ws += (size_t)256 * 4;
    int2*   pair    = (int2*)ws;   ws += (size_t)e * 8;
    ushort* hb      = (ushort*)ws; ws += (size_t)n * 256 * 2;   // bf16 hidden state
    ushort* a2      = (ushort*)ws; ws += (size_t)n * 512 * 2;   // A'' hi|lo [n][512]
    ushort* wt1     = (ushort*)ws; ws += (size_t)256 * 768 * 2;
    ushort* wt2     = (ushort*)ws; ws += (size_t)256 * 768 * 2;
    ushort* wt3     = (ushort*)ws; ws += (size_t)256 * 768 * 2;

    float* outv = (float*)d_out;
    float* h3   = (float*)d_out + n;

    int nb_n = (n + 255) / 256;     // 79
    int nb_e = (e + 255) / 256;

    // CSR build
    init_cnt_kernel<<<nb_n, 256, 0, stream>>>(cnt, n);
    hist_kernel<<<nb_e, 256, 0, stream>>>(col, cnt, e);
    dinv_kernel<<<nb_n, 256, 0, stream>>>(cnt, dinv, n);
    scan_p1_kernel<<<nb_n, 256, 0, stream>>>(cnt, offs, bsum, n);
    scan_p2_kernel<<<1, 256, 0, stream>>>(bsum, nb_n);
    scan_p3_kernel<<<nb_n, 256, 0, stream>>>(offs, bsum, cursor, n);
    scatter_kernel<<<nb_e, 256, 0, stream>>>(row, col, dinv, cursor, pair, e);

    // weight prep + x -> bf16
    wprep_kernel<<<256, 256, 0, stream>>>(W1, wt1);
    wprep_kernel<<<256, 256, 0, stream>>>(Wh, wt2);
    wprep_kernel<<<256, 256, 0, stream>>>(W2, wt3);
    cvt_kernel<<<(n * 32 + 255) / 256, 256, 0, stream>>>(x, hb, n * 32);

    int agrid = (n / 4) * 4;            // 20000 blocks: chunk = bid&3, nodegroup = bid>>2
    dim3 ggrid(4, n / 32);              // col-tile fastest: same-XCD A reuse

    // layer 1
    agg_kernel<<<agrid, 256, 0, stream>>>(hb, offs, cnt, pair, dinv, a2, n);
    gemm_mfma_kernel<true, true><<<ggrid, 256, 0, stream>>>(a2, wt1, b1, hb, n);
    // layer 2
    agg_kernel<<<agrid, 256, 0, stream>>>(hb, offs, cnt, pair, dinv, a2, n);
    gemm_mfma_kernel<true, true><<<ggrid, 256, 0, stream>>>(a2, wt2, bh, hb, n);
    // layer 3 -> h3 (f32) straight into d_out
    agg_kernel<<<agrid, 256, 0, stream>>>(hb, offs, cnt, pair, dinv, a2, n);
    gemm_mfma_kernel<false, false><<<ggrid, 256, 0, stream>>>(a2, wt3, b2, h3, n);
    // decoder
    out_kernel<<<(n + 3) / 4, 256, 0, stream>>>(h3, Wout, bout, outv, n);
}

// Round 11
// 294.016 us; speedup vs baseline: 1.4089x; 1.4089x over previous
//
#include <hip/hip_runtime.h>
#include <hip/hip_bf16.h>

#define NN 20000
#define EE 640000

typedef __attribute__((ext_vector_type(8))) short bf16x8;
typedef __attribute__((ext_vector_type(4))) float f32x4;

__device__ __forceinline__ ushort f2b(float f) {
    __hip_bfloat16 h = __float2bfloat16(f);
    return *(ushort*)&h;
}
__device__ __forceinline__ float b2f(ushort u) {
    __hip_bfloat16 h = *(__hip_bfloat16*)&u;
    return __bfloat162float(h);
}

// accumulate 8 bf16 feats (one 16B vector) scaled by m into acc[8]
__device__ __forceinline__ void acc8(float m, bf16x8 v, float* acc) {
    union { bf16x8 v; unsigned u[4]; } t;
    t.v = v;
    #pragma unroll
    for (int k = 0; k < 4; ++k) {
        acc[2 * k]     = fmaf(m, __uint_as_float(t.u[k] << 16), acc[2 * k]);
        acc[2 * k + 1] = fmaf(m, __uint_as_float(t.u[k] & 0xffff0000u), acc[2 * k + 1]);
    }
}

// async global->LDS, 16B per lane. LDS dest = wave-uniform base + lane*16.
__device__ __forceinline__ void gload16(const ushort* g, ushort* l) {
    __builtin_amdgcn_global_load_lds(
        (const __attribute__((address_space(1))) void*)g,
        (__attribute__((address_space(3))) void*)l, 16, 0, 0);
}

// ---------------- CSR build ----------------

__global__ void init_cnt_kernel(int* __restrict__ cnt, int n) {
    int i = blockIdx.x * 256 + threadIdx.x;
    if (i < n) cnt[i] = 0;
}

__global__ void hist_kernel(const int* __restrict__ col, int* __restrict__ cnt, int e) {
    int i = blockIdx.x * 256 + threadIdx.x;
    if (i < e) atomicAdd(&cnt[col[i]], 1);
}

__global__ void dinv_kernel(const int* __restrict__ cnt, float* __restrict__ dinv, int n) {
    int i = blockIdx.x * 256 + threadIdx.x;
    if (i < n) dinv[i] = rsqrtf((float)(cnt[i] + 1));  // +1 self-loop; always > 0
}

__device__ __forceinline__ int block_exscan(int v) {
    __shared__ int wsum[4];
    int tid = threadIdx.x, lane = tid & 63, w = tid >> 6;
    int x = v;
    #pragma unroll
    for (int d = 1; d < 64; d <<= 1) {
        int y = __shfl_up(x, d, 64);
        if (lane >= d) x += y;
    }
    if (lane == 63) wsum[w] = x;
    __syncthreads();
    if (tid == 0) {
        int s = 0;
        #pragma unroll
        for (int k = 0; k < 4; ++k) { int t = wsum[k]; wsum[k] = s; s += t; }
    }
    __syncthreads();
    return wsum[w] + x - v;
}

__global__ __launch_bounds__(256) void scan_p1_kernel(const int* __restrict__ cnt,
                                                      int* __restrict__ offs,
                                                      int* __restrict__ bsum, int n) {
    int i = blockIdx.x * 256 + threadIdx.x;
    int v = (i < n) ? cnt[i] : 0;
    int e = block_exscan(v);
    if (i < n) offs[i] = e;
    if (threadIdx.x == 255) bsum[blockIdx.x] = e + v;
}

__global__ __launch_bounds__(256) void scan_p2_kernel(int* __restrict__ bsum, int nblk) {
    int t = threadIdx.x;
    int v = (t < nblk) ? bsum[t] : 0;
    int e = block_exscan(v);
    if (t < nblk) bsum[t] = e;
}

__global__ __launch_bounds__(256) void scan_p3_kernel(int* __restrict__ offs,
                                                      const int* __restrict__ bsum,
                                                      int* __restrict__ cursor, int n) {
    int i = blockIdx.x * 256 + threadIdx.x;
    if (i < n) {
        int o = offs[i] + bsum[blockIdx.x];
        offs[i] = o;
        cursor[i] = o;
    }
}

__global__ void scatter_kernel(const int* __restrict__ row, const int* __restrict__ col,
                               const float* __restrict__ dinv, int* __restrict__ cursor,
                               int2* __restrict__ pair, int e) {
    int i = blockIdx.x * 256 + threadIdx.x;
    if (i >= e) return;
    int s = row[i], d = col[i];
    int pos = atomicAdd(&cursor[d], 1);
    int2 p;
    p.x = s;
    p.y = __float_as_int(dinv[s] * dinv[d]);
    pair[pos] = p;
}

// ---------------- x f32 -> bf16 ----------------
__global__ __launch_bounds__(256) void cvt_kernel(const float* __restrict__ x,
                                                  ushort* __restrict__ xb, int total8) {
    int i = blockIdx.x * 256 + threadIdx.x;   // per 8 elements
    if (i >= total8) return;
    float4 a = ((const float4*)x)[2 * i];
    float4 b = ((const float4*)x)[2 * i + 1];
    union { bf16x8 v; ushort s[8]; } o;
    o.s[0] = f2b(a.x); o.s[1] = f2b(a.y); o.s[2] = f2b(a.z); o.s[3] = f2b(a.w);
    o.s[4] = f2b(b.x); o.s[5] = f2b(b.y); o.s[6] = f2b(b.z); o.s[7] = f2b(b.w);
    ((bf16x8*)xb)[i] = o.v;
}

// ---------------- weight prep: W [256][256] f32 -> Wt [256 col][768 kv] bf16 ----------------
__global__ __launch_bounds__(256) void wprep_kernel(const float* __restrict__ W,
                                                    ushort* __restrict__ Wt) {
    int col = blockIdx.x;
    for (int kv = threadIdx.x; kv < 768; kv += 256) {
        int k = kv & 255;
        float w = W[(size_t)k * 256 + col];
        ushort hi = f2b(w);
        ushort out = (kv < 256 || kv >= 512) ? hi : f2b(w - b2f(hi));
        Wt[(size_t)col * 768 + kv] = out;
    }
}

// ---------------- aggregation v7 (proven 45.5us) + truncation-split epilogue ----------------
// hb bf16 [n][256]. chunk = bid&3 (64 feats, slice 2.56MB L2-fit). 4 waves = 4 nodes/block.
// Lane: esub = lane>>3 (8 edges in flight per step), fsub = lane&7 (bf16x8 within chunk).
__global__ __launch_bounds__(256) void agg_kernel(
    const ushort* __restrict__ hb,
    const int* __restrict__ offs, const int* __restrict__ cnt,
    const int2* __restrict__ pair,
    const float* __restrict__ dinv,
    ushort* __restrict__ a2, int n) {
    int chunk = blockIdx.x & 3;
    int node = (blockIdx.x >> 2) * 4 + (threadIdx.x >> 6);
    int lane = threadIdx.x & 63;
    int esub = lane >> 3, fsub = lane & 7;
    const ushort* base = hb + chunk * 64 + fsub * 8;
    const unsigned long long* pq = (const unsigned long long*)pair;

    int beg = offs[node], num = cnt[node];
    float acc[8] = {};

    for (int j = 0; j < num; j += 32) {
        int i0 = j + esub, i1 = j + 8 + esub, i2 = j + 16 + esub, i3 = j + 24 + esub;
        bool p0 = i0 < num, p1 = i1 < num, p2 = i2 < num, p3 = i3 < num;
        unsigned long long q0 = pq[p0 ? beg + i0 : beg];
        unsigned long long q1 = pq[p1 ? beg + i1 : beg];
        unsigned long long q2 = pq[p2 ? beg + i2 : beg];
        unsigned long long q3 = pq[p3 ? beg + i3 : beg];
        int s0 = (int)(q0 & 0xffffffffu), s1 = (int)(q1 & 0xffffffffu);
        int s2 = (int)(q2 & 0xffffffffu), s3 = (int)(q3 & 0xffffffffu);
        float m0 = p0 ? __int_as_float((int)(q0 >> 32)) : 0.f;
        float m1 = p1 ? __int_as_float((int)(q1 >> 32)) : 0.f;
        float m2 = p2 ? __int_as_float((int)(q2 >> 32)) : 0.f;
        float m3 = p3 ? __int_as_float((int)(q3 >> 32)) : 0.f;
        bf16x8 v0 = *(const bf16x8*)(base + (size_t)s0 * 256);
        bf16x8 v1 = *(const bf16x8*)(base + (size_t)s1 * 256);
        bf16x8 v2 = *(const bf16x8*)(base + (size_t)s2 * 256);
        bf16x8 v3 = *(const bf16x8*)(base + (size_t)s3 * 256);
        acc8(m0, v0, acc);
        acc8(m1, v1, acc);
        acc8(m2, v2, acc);
        acc8(m3, v3, acc);
    }

    #pragma unroll
    for (int d = 8; d < 64; d <<= 1)
        #pragma unroll
        for (int k = 0; k < 8; ++k)
            acc[k] += __shfl_xor(acc[k], d, 64);

    if (esub == 0) {   // lanes 0..7 hold fsub 0..7
        float di = dinv[node];
        bf16x8 sv = *(const bf16x8*)(base + (size_t)node * 256);
        acc8(di * di, sv, acc);
        int feat = chunk * 64 + fsub * 8;
        union { bf16x8 v; ushort s[8]; } hi, lo;
        #pragma unroll
        for (int k = 0; k < 8; ++k) {
            unsigned u = __float_as_uint(acc[k]);
            hi.s[k] = (ushort)(u >> 16);                       // truncation hi
            float l = acc[k] - __uint_as_float(u & 0xffff0000u); // exact remainder
            lo.s[k] = (ushort)(__float_as_uint(l) >> 16);
        }
        *(bf16x8*)(a2 + (size_t)node * 512 + feat)       = hi.v;
        *(bf16x8*)(a2 + (size_t)node * 512 + 256 + feat) = lo.v;
    }
}

// ---------------- bf16 MFMA GEMM: 128x128 tile, global_load_lds + XOR-swizzled LDS ----------------
// LDS layout: Ast[row][slot'] where slot' = slot ^ (row&7), slot = 16B chunk of the 64-short K-tile.
// Staging: linear LDS dest (gload_lds requirement) + pre-swizzled global source slot.
// ds_read: same XOR applied -> <=2-way bank conflicts (free).
template<bool RELU, bool BF16OUT>
__global__ __launch_bounds__(256) void gemm_mfma_kernel(
    const ushort* __restrict__ A2, const ushort* __restrict__ Wt,
    const float* __restrict__ bias, void* __restrict__ Cout, int n) {
    __shared__ ushort Ast[128][64];
    __shared__ ushort Bst[128][64];
    int tid = threadIdx.x;
    int lane = tid & 63, wid = tid >> 6;
    int rowbase = blockIdx.x * 128;
    int colbase = blockIdx.y * 128;
    int awr = (wid >> 1) * 64;
    int bwc = (wid & 1) * 64;

    f32x4 zero = {0.f, 0.f, 0.f, 0.f};
    f32x4 acc[4][4];
    #pragma unroll
    for (int m = 0; m < 4; ++m)
        #pragma unroll
        for (int nn = 0; nn < 4; ++nn) acc[m][nn] = zero;

    // staging addresses: call q covers rows wid*32+q*8 .. +8; lane: rsub=lane>>3, s=lane&7
    int rsub = lane >> 3, sl = lane & 7;
    const ushort* asrc[4];
    const ushort* bsrc[4];
    #pragma unroll
    for (int q = 0; q < 4; ++q) {
        int rin = wid * 32 + q * 8 + rsub;
        int c = sl ^ (rin & 7);                 // logical slot this lane fetches
        int grA = min(rowbase + rin, n - 1);
        asrc[q] = A2 + (size_t)grA * 512 + c * 8;
        bsrc[q] = Wt + (size_t)(colbase + rin) * 768 + c * 8;
    }

    for (int kt = 0; kt < 12; ++kt) {
        int kv0 = kt * 64;
        int acol0 = (kv0 < 256) ? kv0 : kv0 - 256;
        #pragma unroll
        for (int q = 0; q < 4; ++q)
            gload16(asrc[q] + acol0, &Ast[wid * 32 + q * 8][0]);
        #pragma unroll
        for (int q = 0; q < 4; ++q)
            gload16(bsrc[q] + kv0, &Bst[wid * 32 + q * 8][0]);
        __syncthreads();   // drains vmcnt -> staged data visible
        #pragma unroll
        for (int kk = 0; kk < 2; ++kk) {
            int clog = kk * 4 + (lane >> 4);
            bf16x8 af[4], bf[4];
            #pragma unroll
            for (int m = 0; m < 4; ++m) {
                int row = awr + m * 16 + (lane & 15);
                af[m] = *(const bf16x8*)&Ast[row][(clog ^ (row & 7)) * 8];
            }
            #pragma unroll
            for (int nn = 0; nn < 4; ++nn) {
                int row = bwc + nn * 16 + (lane & 15);
                bf[nn] = *(const bf16x8*)&Bst[row][(clog ^ (row & 7)) * 8];
            }
            #pragma unroll
            for (int m = 0; m < 4; ++m)
                #pragma unroll
                for (int nn = 0; nn < 4; ++nn)
                    acc[m][nn] = __builtin_amdgcn_mfma_f32_16x16x32_bf16(
                        af[m], bf[nn], acc[m][nn], 0, 0, 0);
        }
        __syncthreads();
    }

    #pragma unroll
    for (int nn = 0; nn < 4; ++nn) {
        int col = colbase + bwc + nn * 16 + (lane & 15);
        float bv = bias[col];
        #pragma unroll
        for (int m = 0; m < 4; ++m) {
            int grow0 = rowbase + awr + m * 16 + ((lane >> 4) << 2);
            f32x4 v = acc[m][nn];
            #pragma unroll
            for (int rr = 0; rr < 4; ++rr) {
                int row = grow0 + rr;
                if (row < n) {
                    float val = v[rr] + bv;
                    if (RELU) val = fmaxf(val, 0.f);
                    if (BF16OUT)
                        ((ushort*)Cout)[(size_t)row * 256 + col] = f2b(val);
                    else
                        ((float*)Cout)[(size_t)row * 256 + col] = val;
                }
            }
        }
    }
}

// ---------------- final projection: out[i] = h3[i,:] . Wout + bout ----------------
__global__ __launch_bounds__(256) void out_kernel(
    const float* __restrict__ h3, const float* __restrict__ Wout,
    const float* __restrict__ bout, float* __restrict__ out, int n) {
    int node = blockIdx.x * 4 + (threadIdx.x >> 6);
    int lane = threadIdx.x & 63;
    if (node >= n) return;
    float4 v = ((const float4*)(h3 + (size_t)node * 256))[lane];
    float4 w = ((const float4*)Wout)[lane];
    float sum = v.x * w.x + v.y * w.y + v.z * w.z + v.w * w.w;
    #pragma unroll
    for (int d = 32; d > 0; d >>= 1) sum += __shfl_down(sum, d, 64);
    if (lane == 0) out[node] = sum + bout[0];
}

extern "C" void kernel_launch(void* const* d_in, const int* in_sizes, int n_in,
                              void* d_out, int out_size, void* d_ws, size_t ws_size,
                              hipStream_t stream) {
    const int n = NN, e = EE;
    const float* x    = (const float*)d_in[0];
    const int*   eidx = (const int*)d_in[1];
    const float* W1   = (const float*)d_in[2];
    const float* b1   = (const float*)d_in[3];
    const float* Wh   = (const float*)d_in[4];
    const float* bh   = (const float*)d_in[5];
    const float* W2   = (const float*)d_in[6];
    const float* b2   = (const float*)d_in[7];
    const float* Wout = (const float*)d_in[8];
    const float* bout = (const float*)d_in[9];
    const int* row = eidx;        // sources
    const int* col = eidx + e;    // destinations

    char* ws = (char*)d_ws;
    int*    cnt     = (int*)ws;    ws += (size_t)n * 4;
    int*    offs    = (int*)ws;    ws += (size_t)n * 4;
    int*    cursor  = (int*)ws;    ws += (size_t)n * 4;
    float*  dinv    = (float*)ws;  ws += (size_t)n * 4;
    int*    bsum    = (int*)ws;    ws += (size_t)256 * 4;
    int2*   pair    = (int2*)ws;   ws += (size_t)e * 8;
    ushort* hb      = (ushort*)ws; ws += (size_t)n * 256 * 2;   // bf16 hidden state
    ushort* a2      = (ushort*)ws; ws += (size_t)n * 512 * 2;   // A'' hi|lo [n][512]
    ushort* wt1     = (ushort*)ws; ws += (size_t)256 * 768 * 2;
    ushort* wt2     = (ushort*)ws; ws += (size_t)256 * 768 * 2;
    ushort* wt3     = (ushort*)ws; ws += (size_t)256 * 768 * 2;

    float* outv = (float*)d_out;
    float* h3   = (float*)d_out + n;

    int nb_n = (n + 255) / 256;     // 79
    int nb_e = (e + 255) / 256;

    // CSR build
    init_cnt_kernel<<<nb_n, 256, 0, stream>>>(cnt, n);
    hist_kernel<<<nb_e, 256, 0, stream>>>(col, cnt, e);
    dinv_kernel<<<nb_n, 256, 0, stream>>>(cnt, dinv, n);
    scan_p1_kernel<<<nb_n, 256, 0, stream>>>(cnt, offs, bsum, n);
    scan_p2_kernel<<<1, 256, 0, stream>>>(bsum, nb_n);
    scan_p3_kernel<<<nb_n, 256, 0, stream>>>(offs, bsum, cursor, n);
    scatter_kernel<<<nb_e, 256, 0, stream>>>(row, col, dinv, cursor, pair, e);

    // weight prep + x -> bf16
    wprep_kernel<<<256, 256, 0, stream>>>(W1, wt1);
    wprep_kernel<<<256, 256, 0, stream>>>(Wh, wt2);
    wprep_kernel<<<256, 256, 0, stream>>>(W2, wt3);
    cvt_kernel<<<(n * 32 + 255) / 256, 256, 0, stream>>>(x, hb, n * 32);

    int agrid = (n / 4) * 4;            // 20000 blocks: chunk = bid&3, nodegroup = bid>>2
    dim3 ggrid((n + 127) / 128, 2);     // (157, 2)

    // layer 1
    agg_kernel<<<agrid, 256, 0, stream>>>(hb, offs, cnt, pair, dinv, a2, n);
    gemm_mfma_kernel<true, true><<<ggrid, 256, 0, stream>>>(a2, wt1, b1, hb, n);
    // layer 2
    agg_kernel<<<agrid, 256, 0, stream>>>(hb, offs, cnt, pair, dinv, a2, n);
    gemm_mfma_kernel<true, true><<<ggrid, 256, 0, stream>>>(a2, wt2, bh, hb, n);
    // layer 3 -> h3 (f32) straight into d_out
    agg_kernel<<<agrid, 256, 0, stream>>>(hb, offs, cnt, pair, dinv, a2, n);
    gemm_mfma_kernel<false, false><<<ggrid, 256, 0, stream>>>(a2, wt3, b2, h3, n);
    // decoder
    out_kernel<<<(n + 3) / 4, 256, 0, stream>>>(h3, Wout, bout, outv, n);
}

// Round 12
// 269.615 us; speedup vs baseline: 1.5364x; 1.0905x over previous
//
#include <hip/hip_runtime.h>
#include <hip/hip_bf16.h>

#define NN 20000
#define EE 640000

typedef __attribute__((ext_vector_type(8))) short bf16x8;
typedef __attribute__((ext_vector_type(4))) float f32x4;

__device__ __forceinline__ ushort f2b(float f) {
    __hip_bfloat16 h = __float2bfloat16(f);
    return *(ushort*)&h;
}
__device__ __forceinline__ float b2f(ushort u) {
    __hip_bfloat16 h = *(__hip_bfloat16*)&u;
    return __bfloat162float(h);
}

// accumulate 8 bf16 feats (one 16B vector) scaled by m into acc[8]
__device__ __forceinline__ void acc8(float m, bf16x8 v, float* acc) {
    union { bf16x8 v; unsigned u[4]; } t;
    t.v = v;
    #pragma unroll
    for (int k = 0; k < 4; ++k) {
        acc[2 * k]     = fmaf(m, __uint_as_float(t.u[k] << 16), acc[2 * k]);
        acc[2 * k + 1] = fmaf(m, __uint_as_float(t.u[k] & 0xffff0000u), acc[2 * k + 1]);
    }
}

// async global->LDS, 16B per lane. LDS dest = wave-uniform base + lane*16.
__device__ __forceinline__ void gload16(const ushort* g, ushort* l) {
    __builtin_amdgcn_global_load_lds(
        (const __attribute__((address_space(1))) void*)g,
        (__attribute__((address_space(3))) void*)l, 16, 0, 0);
}

// ---------------- CSR build ----------------

__global__ void init_cnt_kernel(int* __restrict__ cnt, int n) {
    int i = blockIdx.x * 256 + threadIdx.x;
    if (i < n) cnt[i] = 0;
}

__global__ void hist_kernel(const int* __restrict__ col, int* __restrict__ cnt, int e) {
    int i = blockIdx.x * 256 + threadIdx.x;
    if (i < e) atomicAdd(&cnt[col[i]], 1);
}

__global__ void dinv_kernel(const int* __restrict__ cnt, float* __restrict__ dinv, int n) {
    int i = blockIdx.x * 256 + threadIdx.x;
    if (i < n) dinv[i] = rsqrtf((float)(cnt[i] + 1));  // +1 self-loop; always > 0
}

__device__ __forceinline__ int block_exscan(int v) {
    __shared__ int wsum[4];
    int tid = threadIdx.x, lane = tid & 63, w = tid >> 6;
    int x = v;
    #pragma unroll
    for (int d = 1; d < 64; d <<= 1) {
        int y = __shfl_up(x, d, 64);
        if (lane >= d) x += y;
    }
    if (lane == 63) wsum[w] = x;
    __syncthreads();
    if (tid == 0) {
        int s = 0;
        #pragma unroll
        for (int k = 0; k < 4; ++k) { int t = wsum[k]; wsum[k] = s; s += t; }
    }
    __syncthreads();
    return wsum[w] + x - v;
}

__global__ __launch_bounds__(256) void scan_p1_kernel(const int* __restrict__ cnt,
                                                      int* __restrict__ offs,
                                                      int* __restrict__ bsum, int n) {
    int i = blockIdx.x * 256 + threadIdx.x;
    int v = (i < n) ? cnt[i] : 0;
    int e = block_exscan(v);
    if (i < n) offs[i] = e;
    if (threadIdx.x == 255) bsum[blockIdx.x] = e + v;
}

__global__ __launch_bounds__(256) void scan_p2_kernel(int* __restrict__ bsum, int nblk) {
    int t = threadIdx.x;
    int v = (t < nblk) ? bsum[t] : 0;
    int e = block_exscan(v);
    if (t < nblk) bsum[t] = e;
}

__global__ __launch_bounds__(256) void scan_p3_kernel(int* __restrict__ offs,
                                                      const int* __restrict__ bsum,
                                                      int* __restrict__ cursor, int n) {
    int i = blockIdx.x * 256 + threadIdx.x;
    if (i < n) {
        int o = offs[i] + bsum[blockIdx.x];
        offs[i] = o;
        cursor[i] = o;
    }
}

__global__ void scatter_kernel(const int* __restrict__ row, const int* __restrict__ col,
                               const float* __restrict__ dinv, int* __restrict__ cursor,
                               int2* __restrict__ pair, int e) {
    int i = blockIdx.x * 256 + threadIdx.x;
    if (i >= e) return;
    int s = row[i], d = col[i];
    int pos = atomicAdd(&cursor[d], 1);
    int2 p;
    p.x = s;
    p.y = __float_as_int(dinv[s] * dinv[d]);
    pair[pos] = p;
}

// ---------------- x f32 -> bf16 ----------------
__global__ __launch_bounds__(256) void cvt_kernel(const float* __restrict__ x,
                                                  ushort* __restrict__ xb, int total8) {
    int i = blockIdx.x * 256 + threadIdx.x;   // per 8 elements
    if (i >= total8) return;
    float4 a = ((const float4*)x)[2 * i];
    float4 b = ((const float4*)x)[2 * i + 1];
    union { bf16x8 v; ushort s[8]; } o;
    o.s[0] = f2b(a.x); o.s[1] = f2b(a.y); o.s[2] = f2b(a.z); o.s[3] = f2b(a.w);
    o.s[4] = f2b(b.x); o.s[5] = f2b(b.y); o.s[6] = f2b(b.z); o.s[7] = f2b(b.w);
    ((bf16x8*)xb)[i] = o.v;
}

// ---------------- weight prep: all 3 weights in one launch ----------------
// W [256][256] f32 -> Wt[w] [256 col][768 kv] bf16 (hi | lo | hi)
__global__ __launch_bounds__(256) void wprep_kernel(const float* __restrict__ W1,
                                                    const float* __restrict__ Wh,
                                                    const float* __restrict__ W2,
                                                    ushort* __restrict__ Wt) {
    const float* W = (blockIdx.y == 0) ? W1 : ((blockIdx.y == 1) ? Wh : W2);
    ushort* dst = Wt + (size_t)blockIdx.y * 256 * 768;
    int col = blockIdx.x;
    for (int kv = threadIdx.x; kv < 768; kv += 256) {
        int k = kv & 255;
        float w = W[(size_t)k * 256 + col];
        ushort hi = f2b(w);
        ushort out = (kv < 256 || kv >= 512) ? hi : f2b(w - b2f(hi));
        dst[(size_t)col * 768 + kv] = out;
    }
}

// ---------------- aggregation v9: 2 nodes per wave, 64-feat chunks ----------------
// hb bf16 [n][256]. chunk = bid&3 (slice 2.56MB, XCD-pinned). 4 waves x 2 nodes = 8 nodes/block.
// Lane: half = lane>>5 (node), esub = (lane>>3)&3 (4 edge slots), fsub = lane&7 (bf16x8).
// Per iter: 16 edge slots/node, 32 gathers in flight per wave. Epilogue amortized over 2 nodes.
__global__ __launch_bounds__(256) void agg_kernel(
    const ushort* __restrict__ hb,
    const int* __restrict__ offs, const int* __restrict__ cnt,
    const int2* __restrict__ pair,
    const float* __restrict__ dinv,
    ushort* __restrict__ a2, int n) {
    int chunk = blockIdx.x & 3;
    int lane = threadIdx.x & 63;
    int half = lane >> 5;
    int esub = (lane >> 3) & 3;
    int fsub = lane & 7;
    int node = (blockIdx.x >> 2) * 8 + (threadIdx.x >> 6) * 2 + half;  // n%8==0
    const ushort* base = hb + chunk * 64 + fsub * 8;
    const unsigned long long* pq = (const unsigned long long*)pair;

    int beg = offs[node], num = cnt[node];
    int maxnum = num;
    #pragma unroll
    for (int d = 8; d < 64; d <<= 1)
        maxnum = max(maxnum, __shfl_xor(maxnum, d, 64));

    float acc[8] = {};
    for (int j = 0; j < maxnum; j += 16) {
        #pragma unroll
        for (int u = 0; u < 4; ++u) {
            int i = j + u * 4 + esub;
            bool p = i < num;
            unsigned long long q = pq[p ? beg + i : beg];
            float m = p ? __int_as_float((int)(q >> 32)) : 0.f;
            int s = (int)(q & 0xffffffffu);
            bf16x8 v = *(const bf16x8*)(base + (size_t)s * 256);
            acc8(m, v, acc);
        }
    }

    // reduce across the 4 esub groups within each 32-lane half (2 butterfly steps)
    #pragma unroll
    for (int d = 8; d < 32; d <<= 1)
        #pragma unroll
        for (int k = 0; k < 8; ++k)
            acc[k] += __shfl_xor(acc[k], d, 64);

    if (esub == 0) {   // lanes 0-7 (node A) and 32-39 (node B) hold fsub 0..7
        float di = dinv[node];
        bf16x8 sv = *(const bf16x8*)(base + (size_t)node * 256);
        acc8(di * di, sv, acc);
        int feat = chunk * 64 + fsub * 8;
        union { bf16x8 v; ushort s[8]; } hi, lo;
        #pragma unroll
        for (int k = 0; k < 8; ++k) {
            unsigned u = __float_as_uint(acc[k]);
            hi.s[k] = (ushort)(u >> 16);                         // truncation hi
            float l = acc[k] - __uint_as_float(u & 0xffff0000u); // exact remainder
            lo.s[k] = (ushort)(__float_as_uint(l) >> 16);
        }
        *(bf16x8*)(a2 + (size_t)node * 512 + feat)       = hi.v;
        *(bf16x8*)(a2 + (size_t)node * 512 + 256 + feat) = lo.v;
    }
}

// ---------------- bf16 MFMA GEMM: 128x64 tile, LDS double-buffer, counted vmcnt ----------------
// Pipeline per kt: stage(kt+1 -> buf^1) ; s_waitcnt vmcnt(6) (buf's 6 loads done, 6 stay
// in flight ACROSS the barrier) ; s_barrier ; compute(buf) ; s_barrier.
// XOR-swizzle (T2): linear LDS dest (gload_lds) + pre-swizzled global slot + swizzled ds_read.
template<bool RELU, bool BF16OUT>
__global__ __launch_bounds__(256) void gemm_mfma_kernel(
    const ushort* __restrict__ A2, const ushort* __restrict__ Wt,
    const float* __restrict__ bias, void* __restrict__ Cout, int n) {
    __shared__ ushort Ast[2][128][64];
    __shared__ ushort Bst[2][64][64];
    int tid = threadIdx.x;
    int lane = tid & 63, wid = tid >> 6;
    int rowbase = blockIdx.x * 128;
    int colbase = blockIdx.y * 64;

    f32x4 zero = {0.f, 0.f, 0.f, 0.f};
    f32x4 acc[2][4];
    #pragma unroll
    for (int m = 0; m < 2; ++m)
        #pragma unroll
        for (int nn = 0; nn < 4; ++nn) acc[m][nn] = zero;

    // staging sources: lane covers (row = 8*q-group + lane>>3, 16B slot = lane&7), pre-swizzled
    int rsub = lane >> 3, sl = lane & 7;
    const ushort* asrc[4];
    #pragma unroll
    for (int q = 0; q < 4; ++q) {
        int rin = wid * 32 + q * 8 + rsub;
        int c = sl ^ (rin & 7);
        int gr = min(rowbase + rin, n - 1);
        asrc[q] = A2 + (size_t)gr * 512 + c * 8;
    }
    const ushort* bsrc[2];
    #pragma unroll
    for (int q = 0; q < 2; ++q) {
        int rin = wid * 16 + q * 8 + rsub;
        int c = sl ^ (rin & 7);
        bsrc[q] = Wt + (size_t)(colbase + rin) * 768 + c * 8;
    }

    auto stage = [&](int kt, int buf) {
        int kv0 = kt * 64;
        int acol0 = (kv0 < 256) ? kv0 : kv0 - 256;
        #pragma unroll
        for (int q = 0; q < 4; ++q)
            gload16(asrc[q] + acol0, &Ast[buf][wid * 32 + q * 8][0]);
        #pragma unroll
        for (int q = 0; q < 2; ++q)
            gload16(bsrc[q] + kv0, &Bst[buf][wid * 16 + q * 8][0]);
    };

    stage(0, 0);
    for (int kt = 0; kt < 12; ++kt) {
        int cur = kt & 1;
        if (kt < 11) {
            stage(kt + 1, cur ^ 1);
            asm volatile("s_waitcnt vmcnt(6)" ::: "memory");
        } else {
            asm volatile("s_waitcnt vmcnt(0)" ::: "memory");
        }
        __builtin_amdgcn_s_barrier();
        #pragma unroll
        for (int kk = 0; kk < 2; ++kk) {
            int clog = kk * 4 + (lane >> 4);
            bf16x8 af[2], bf[4];
            #pragma unroll
            for (int m = 0; m < 2; ++m) {
                int row = wid * 32 + m * 16 + (lane & 15);
                af[m] = *(const bf16x8*)&Ast[cur][row][(clog ^ (row & 7)) * 8];
            }
            #pragma unroll
            for (int nn = 0; nn < 4; ++nn) {
                int row = nn * 16 + (lane & 15);
                bf[nn] = *(const bf16x8*)&Bst[cur][row][(clog ^ (row & 7)) * 8];
            }
            #pragma unroll
            for (int m = 0; m < 2; ++m)
                #pragma unroll
                for (int nn = 0; nn < 4; ++nn)
                    acc[m][nn] = __builtin_amdgcn_mfma_f32_16x16x32_bf16(
                        af[m], bf[nn], acc[m][nn], 0, 0, 0);
        }
        __builtin_amdgcn_s_barrier();   // all reads of `cur` done before it's restaged
    }

    #pragma unroll
    for (int nn = 0; nn < 4; ++nn) {
        int col = colbase + nn * 16 + (lane & 15);
        float bv = bias[col];
        #pragma unroll
        for (int m = 0; m < 2; ++m) {
            int grow0 = rowbase + wid * 32 + m * 16 + ((lane >> 4) << 2);
            f32x4 v = acc[m][nn];
            #pragma unroll
            for (int rr = 0; rr < 4; ++rr) {
                int row = grow0 + rr;
                if (row < n) {
                    float val = v[rr] + bv;
                    if (RELU) val = fmaxf(val, 0.f);
                    if (BF16OUT)
                        ((ushort*)Cout)[(size_t)row * 256 + col] = f2b(val);
                    else
                        ((float*)Cout)[(size_t)row * 256 + col] = val;
                }
            }
        }
    }
}

// ---------------- final projection: out[i] = h3[i,:] . Wout + bout ----------------
__global__ __launch_bounds__(256) void out_kernel(
    const float* __restrict__ h3, const float* __restrict__ Wout,
    const float* __restrict__ bout, float* __restrict__ out, int n) {
    int node = blockIdx.x * 4 + (threadIdx.x >> 6);
    int lane = threadIdx.x & 63;
    if (node >= n) return;
    float4 v = ((const float4*)(h3 + (size_t)node * 256))[lane];
    float4 w = ((const float4*)Wout)[lane];
    float sum = v.x * w.x + v.y * w.y + v.z * w.z + v.w * w.w;
    #pragma unroll
    for (int d = 32; d > 0; d >>= 1) sum += __shfl_down(sum, d, 64);
    if (lane == 0) out[node] = sum + bout[0];
}

extern "C" void kernel_launch(void* const* d_in, const int* in_sizes, int n_in,
                              void* d_out, int out_size, void* d_ws, size_t ws_size,
                              hipStream_t stream) {
    const int n = NN, e = EE;
    const float* x    = (const float*)d_in[0];
    const int*   eidx = (const int*)d_in[1];
    const float* W1   = (const float*)d_in[2];
    const float* b1   = (const float*)d_in[3];
    const float* Wh   = (const float*)d_in[4];
    const float* bh   = (const float*)d_in[5];
    const float* W2   = (const float*)d_in[6];
    const float* b2   = (const float*)d_in[7];
    const float* Wout = (const float*)d_in[8];
    const float* bout = (const float*)d_in[9];
    const int* row = eidx;        // sources
    const int* col = eidx + e;    // destinations

    char* ws = (char*)d_ws;
    int*    cnt     = (int*)ws;    ws += (size_t)n * 4;
    int*    offs    = (int*)ws;    ws += (size_t)n * 4;
    int*    cursor  = (int*)ws;    ws += (size_t)n * 4;
    float*  dinv    = (float*)ws;  ws += (size_t)n * 4;
    int*    bsum    = (int*)ws;    ws += (size_t)256 * 4;
    int2*   pair    = (int2*)ws;   ws += (size_t)e * 8;
    ushort* hb      = (ushort*)ws; ws += (size_t)n * 256 * 2;   // bf16 hidden state
    ushort* a2      = (ushort*)ws; ws += (size_t)n * 512 * 2;   // A'' hi|lo [n][512]
    ushort* wt      = (ushort*)ws; ws += (size_t)3 * 256 * 768 * 2;
    ushort* wt1 = wt;
    ushort* wt2 = wt + (size_t)256 * 768;
    ushort* wt3 = wt + (size_t)2 * 256 * 768;

    float* outv = (float*)d_out;
    float* h3   = (float*)d_out + n;

    int nb_n = (n + 255) / 256;     // 79
    int nb_e = (e + 255) / 256;

    // CSR build
    init_cnt_kernel<<<nb_n, 256, 0, stream>>>(cnt, n);
    hist_kernel<<<nb_e, 256, 0, stream>>>(col, cnt, e);
    dinv_kernel<<<nb_n, 256, 0, stream>>>(cnt, dinv, n);
    scan_p1_kernel<<<nb_n, 256, 0, stream>>>(cnt, offs, bsum, n);
    scan_p2_kernel<<<1, 256, 0, stream>>>(bsum, nb_n);
    scan_p3_kernel<<<nb_n, 256, 0, stream>>>(offs, bsum, cursor, n);
    scatter_kernel<<<nb_e, 256, 0, stream>>>(row, col, dinv, cursor, pair, e);

    // weight prep (1 launch) + x -> bf16
    wprep_kernel<<<dim3(256, 3), 256, 0, stream>>>(W1, Wh, W2, wt);
    cvt_kernel<<<(n * 32 + 255) / 256, 256, 0, stream>>>(x, hb, n * 32);

    int agrid = (n / 8) * 4;            // 10000 blocks: chunk = bid&3, nodegroup = bid>>2
    dim3 ggrid((n + 127) / 128, 4);     // (157, 4) = 628 blocks

    // layer 1
    agg_kernel<<<agrid, 256, 0, stream>>>(hb, offs, cnt, pair, dinv, a2, n);
    gemm_mfma_kernel<true, true><<<ggrid, 256, 0, stream>>>(a2, wt1, b1, hb, n);
    // layer 2
    agg_kernel<<<agrid, 256, 0, stream>>>(hb, offs, cnt, pair, dinv, a2, n);
    gemm_mfma_kernel<true, true><<<ggrid, 256, 0, stream>>>(a2, wt2, bh, hb, n);
    // layer 3 -> h3 (f32) straight into d_out
    agg_kernel<<<agrid, 256, 0, stream>>>(hb, offs, cnt, pair, dinv, a2, n);
    gemm_mfma_kernel<false, false><<<ggrid, 256, 0, stream>>>(a2, wt3, b2, h3, n);
    // decoder
    out_kernel<<<(n + 3) / 4, 256, 0, stream>>>(h3, Wout, bout, outv, n);
}

// Round 13
// 255.926 us; speedup vs baseline: 1.6186x; 1.0535x over previous
//
#include <hip/hip_runtime.h>
#include <hip/hip_bf16.h>

#define NN 20000
#define EE 640000

typedef __attribute__((ext_vector_type(8))) short bf16x8;
typedef __attribute__((ext_vector_type(4))) float f32x4;

__device__ __forceinline__ ushort f2b(float f) {
    __hip_bfloat16 h = __float2bfloat16(f);
    return *(ushort*)&h;
}
__device__ __forceinline__ float b2f(ushort u) {
    __hip_bfloat16 h = *(__hip_bfloat16*)&u;
    return __bfloat162float(h);
}

// accumulate 8 bf16 feats (one 16B vector) scaled by m into acc[8]
__device__ __forceinline__ void acc8(float m, bf16x8 v, float* acc) {
    union { bf16x8 v; unsigned u[4]; } t;
    t.v = v;
    #pragma unroll
    for (int k = 0; k < 4; ++k) {
        acc[2 * k]     = fmaf(m, __uint_as_float(t.u[k] << 16), acc[2 * k]);
        acc[2 * k + 1] = fmaf(m, __uint_as_float(t.u[k] & 0xffff0000u), acc[2 * k + 1]);
    }
}

// async global->LDS, 16B per lane. LDS dest = wave-uniform base + lane*16.
__device__ __forceinline__ void gload16(const ushort* g, ushort* l) {
    __builtin_amdgcn_global_load_lds(
        (const __attribute__((address_space(1))) void*)g,
        (__attribute__((address_space(3))) void*)l, 16, 0, 0);
}

// ---------------- CSR build ----------------

__global__ void init_cnt_kernel(int* __restrict__ cnt, int n) {
    int i = blockIdx.x * 256 + threadIdx.x;
    if (i < n) cnt[i] = 0;
}

__global__ void hist_kernel(const int* __restrict__ col, int* __restrict__ cnt, int e) {
    int i = blockIdx.x * 256 + threadIdx.x;
    if (i < e) atomicAdd(&cnt[col[i]], 1);
}

__device__ __forceinline__ int block_exscan(int v) {
    __shared__ int wsum[4];
    int tid = threadIdx.x, lane = tid & 63, w = tid >> 6;
    int x = v;
    #pragma unroll
    for (int d = 1; d < 64; d <<= 1) {
        int y = __shfl_up(x, d, 64);
        if (lane >= d) x += y;
    }
    if (lane == 63) wsum[w] = x;
    __syncthreads();
    if (tid == 0) {
        int s = 0;
        #pragma unroll
        for (int k = 0; k < 4; ++k) { int t = wsum[k]; wsum[k] = s; s += t; }
    }
    __syncthreads();
    return wsum[w] + x - v;
}

// scan phase 1 + dinv fused
__global__ __launch_bounds__(256) void scan_p1_kernel(const int* __restrict__ cnt,
                                                      int* __restrict__ offs,
                                                      int* __restrict__ bsum,
                                                      float* __restrict__ dinv, int n) {
    int i = blockIdx.x * 256 + threadIdx.x;
    int v = (i < n) ? cnt[i] : 0;
    int e = block_exscan(v);
    if (i < n) {
        offs[i] = e;
        dinv[i] = rsqrtf((float)(v + 1));   // +1 self-loop; always > 0
    }
    if (threadIdx.x == 255) bsum[blockIdx.x] = e + v;
}

__global__ __launch_bounds__(256) void scan_p2_kernel(int* __restrict__ bsum, int nblk) {
    int t = threadIdx.x;
    int v = (t < nblk) ? bsum[t] : 0;
    int e = block_exscan(v);
    if (t < nblk) bsum[t] = e;
}

__global__ __launch_bounds__(256) void scan_p3_kernel(int* __restrict__ offs,
                                                      const int* __restrict__ bsum,
                                                      int* __restrict__ cursor, int n) {
    int i = blockIdx.x * 256 + threadIdx.x;
    if (i < n) {
        int o = offs[i] + bsum[blockIdx.x];
        offs[i] = o;
        cursor[i] = o;
    }
}

// pack: hi16 = bf16(norm), lo16 = src id (n < 65536)
__global__ void scatter_kernel(const int* __restrict__ row, const int* __restrict__ col,
                               const float* __restrict__ dinv, int* __restrict__ cursor,
                               unsigned* __restrict__ pq, int e) {
    int i = blockIdx.x * 256 + threadIdx.x;
    if (i >= e) return;
    int s = row[i], d = col[i];
    int pos = atomicAdd(&cursor[d], 1);
    unsigned nb = f2b(dinv[s] * dinv[d]);
    pq[pos] = (nb << 16) | (unsigned)s;
}

// ---------------- x f32 -> bf16 ----------------
__global__ __launch_bounds__(256) void cvt_kernel(const float* __restrict__ x,
                                                  ushort* __restrict__ xb, int total8) {
    int i = blockIdx.x * 256 + threadIdx.x;   // per 8 elements
    if (i >= total8) return;
    float4 a = ((const float4*)x)[2 * i];
    float4 b = ((const float4*)x)[2 * i + 1];
    union { bf16x8 v; ushort s[8]; } o;
    o.s[0] = f2b(a.x); o.s[1] = f2b(a.y); o.s[2] = f2b(a.z); o.s[3] = f2b(a.w);
    o.s[4] = f2b(b.x); o.s[5] = f2b(b.y); o.s[6] = f2b(b.z); o.s[7] = f2b(b.w);
    ((bf16x8*)xb)[i] = o.v;
}

// ---------------- weight prep: all 3 weights in one launch ----------------
__global__ __launch_bounds__(256) void wprep_kernel(const float* __restrict__ W1,
                                                    const float* __restrict__ Wh,
                                                    const float* __restrict__ W2,
                                                    ushort* __restrict__ Wt) {
    const float* W = (blockIdx.y == 0) ? W1 : ((blockIdx.y == 1) ? Wh : W2);
    ushort* dst = Wt + (size_t)blockIdx.y * 256 * 768;
    int col = blockIdx.x;
    for (int kv = threadIdx.x; kv < 768; kv += 256) {
        int k = kv & 255;
        float w = W[(size_t)k * 256 + col];
        ushort hi = f2b(w);
        ushort out = (kv < 256 || kv >= 512) ? hi : f2b(w - b2f(hi));
        dst[(size_t)col * 768 + kv] = out;
    }
}

// ---------------- aggregation v10: 2 nodes/wave + packed meta + meta pipeline ----------------
// hb bf16 [n][256]. chunk = bid&3 (slice 2.56MB, XCD-pinned). 4 waves x 2 nodes = 8 nodes/block.
// Lane: half = lane>>5 (node), esub = (lane>>3)&3 (4 edge slots), fsub = lane&7 (bf16x8).
// Metadata for iter j+1 loaded while gathering iter j -> gather latency only on critical path.
__global__ __launch_bounds__(256) void agg_kernel(
    const ushort* __restrict__ hb,
    const int* __restrict__ offs, const int* __restrict__ cnt,
    const unsigned* __restrict__ pq,
    const float* __restrict__ dinv,
    ushort* __restrict__ a2, int n) {
    int chunk = blockIdx.x & 3;
    int lane = threadIdx.x & 63;
    int half = lane >> 5;
    int esub = (lane >> 3) & 3;
    int fsub = lane & 7;
    int node = (blockIdx.x >> 2) * 8 + (threadIdx.x >> 6) * 2 + half;  // n%8==0
    const ushort* base = hb + chunk * 64 + fsub * 8;

    int beg = offs[node], num = cnt[node];
    float acc[8] = {};

    int e0 = esub, e1 = 4 + esub, e2 = 8 + esub, e3 = 12 + esub;
    unsigned q0 = pq[e0 < num ? beg + e0 : 0];
    unsigned q1 = pq[e1 < num ? beg + e1 : 0];
    unsigned q2 = pq[e2 < num ? beg + e2 : 0];
    unsigned q3 = pq[e3 < num ? beg + e3 : 0];

    for (int j = 0; j < num; j += 16) {
        int jn = j + 16;
        int k0 = jn + esub, k1 = jn + 4 + esub, k2 = jn + 8 + esub, k3 = jn + 12 + esub;
        unsigned p0 = pq[k0 < num ? beg + k0 : 0];
        unsigned p1 = pq[k1 < num ? beg + k1 : 0];
        unsigned p2 = pq[k2 < num ? beg + k2 : 0];
        unsigned p3 = pq[k3 < num ? beg + k3 : 0];

        float m0 = (j +      esub) < num ? __uint_as_float(q0 & 0xffff0000u) : 0.f;
        float m1 = (j + 4  + esub) < num ? __uint_as_float(q1 & 0xffff0000u) : 0.f;
        float m2 = (j + 8  + esub) < num ? __uint_as_float(q2 & 0xffff0000u) : 0.f;
        float m3 = (j + 12 + esub) < num ? __uint_as_float(q3 & 0xffff0000u) : 0.f;
        bf16x8 v0 = *(const bf16x8*)(base + (size_t)(q0 & 0xffffu) * 256);
        bf16x8 v1 = *(const bf16x8*)(base + (size_t)(q1 & 0xffffu) * 256);
        bf16x8 v2 = *(const bf16x8*)(base + (size_t)(q2 & 0xffffu) * 256);
        bf16x8 v3 = *(const bf16x8*)(base + (size_t)(q3 & 0xffffu) * 256);
        acc8(m0, v0, acc);
        acc8(m1, v1, acc);
        acc8(m2, v2, acc);
        acc8(m3, v3, acc);
        q0 = p0; q1 = p1; q2 = p2; q3 = p3;
    }

    // reduce across the 4 esub groups within each 32-lane half
    #pragma unroll
    for (int d = 8; d < 32; d <<= 1)
        #pragma unroll
        for (int k = 0; k < 8; ++k)
            acc[k] += __shfl_xor(acc[k], d, 64);

    if (esub == 0) {   // lanes 0-7 (node A) and 32-39 (node B) hold fsub 0..7
        float di = dinv[node];
        bf16x8 sv = *(const bf16x8*)(base + (size_t)node * 256);
        acc8(di * di, sv, acc);
        int feat = chunk * 64 + fsub * 8;
        union { bf16x8 v; ushort s[8]; } hi, lo;
        #pragma unroll
        for (int k = 0; k < 8; ++k) {
            unsigned u = __float_as_uint(acc[k]);
            hi.s[k] = (ushort)(u >> 16);                         // truncation hi
            float l = acc[k] - __uint_as_float(u & 0xffff0000u); // exact remainder
            lo.s[k] = (ushort)(__float_as_uint(l) >> 16);
        }
        *(bf16x8*)(a2 + (size_t)node * 512 + feat)       = hi.v;
        *(bf16x8*)(a2 + (size_t)node * 512 + 256 + feat) = lo.v;
    }
}

// ---------------- init out with bias (for fused decoder atomics) ----------------
__global__ void init_out_kernel(float* __restrict__ out, const float* __restrict__ bout, int n) {
    int i = blockIdx.x * 256 + threadIdx.x;
    if (i < n) out[i] = bout[0];
}

// ---------------- bf16 MFMA GEMM: 128x64 tile, LDS dbuf, counted vmcnt ----------------
// FUSE: also accumulate out[row] += sum_cols(C[row,col]*Wout[col]) via lane-reduce + atomicAdd.
template<bool RELU, bool BF16OUT, bool FUSE>
__global__ __launch_bounds__(256) void gemm_mfma_kernel(
    const ushort* __restrict__ A2, const ushort* __restrict__ Wt,
    const float* __restrict__ bias, void* __restrict__ Cout,
    const float* __restrict__ Wout, float* __restrict__ outv, int n) {
    __shared__ ushort Ast[2][128][64];
    __shared__ ushort Bst[2][64][64];
    int tid = threadIdx.x;
    int lane = tid & 63, wid = tid >> 6;
    int rowbase = blockIdx.x * 128;
    int colbase = blockIdx.y * 64;

    f32x4 zero = {0.f, 0.f, 0.f, 0.f};
    f32x4 acc[2][4];
    #pragma unroll
    for (int m = 0; m < 2; ++m)
        #pragma unroll
        for (int nn = 0; nn < 4; ++nn) acc[m][nn] = zero;

    // staging sources: lane covers (row = 8*q-group + lane>>3, 16B slot = lane&7), pre-swizzled
    int rsub = lane >> 3, sl = lane & 7;
    const ushort* asrc[4];
    #pragma unroll
    for (int q = 0; q < 4; ++q) {
        int rin = wid * 32 + q * 8 + rsub;
        int c = sl ^ (rin & 7);
        int gr = min(rowbase + rin, n - 1);
        asrc[q] = A2 + (size_t)gr * 512 + c * 8;
    }
    const ushort* bsrc[2];
    #pragma unroll
    for (int q = 0; q < 2; ++q) {
        int rin = wid * 16 + q * 8 + rsub;
        int c = sl ^ (rin & 7);
        bsrc[q] = Wt + (size_t)(colbase + rin) * 768 + c * 8;
    }

    auto stage = [&](int kt, int buf) {
        int kv0 = kt * 64;
        int acol0 = (kv0 < 256) ? kv0 : kv0 - 256;
        #pragma unroll
        for (int q = 0; q < 4; ++q)
            gload16(asrc[q] + acol0, &Ast[buf][wid * 32 + q * 8][0]);
        #pragma unroll
        for (int q = 0; q < 2; ++q)
            gload16(bsrc[q] + kv0, &Bst[buf][wid * 16 + q * 8][0]);
    };

    stage(0, 0);
    for (int kt = 0; kt < 12; ++kt) {
        int cur = kt & 1;
        if (kt < 11) {
            stage(kt + 1, cur ^ 1);
            asm volatile("s_waitcnt vmcnt(6)" ::: "memory");
        } else {
            asm volatile("s_waitcnt vmcnt(0)" ::: "memory");
        }
        __builtin_amdgcn_s_barrier();
        #pragma unroll
        for (int kk = 0; kk < 2; ++kk) {
            int clog = kk * 4 + (lane >> 4);
            bf16x8 af[2], bf[4];
            #pragma unroll
            for (int m = 0; m < 2; ++m) {
                int row = wid * 32 + m * 16 + (lane & 15);
                af[m] = *(const bf16x8*)&Ast[cur][row][(clog ^ (row & 7)) * 8];
            }
            #pragma unroll
            for (int nn = 0; nn < 4; ++nn) {
                int row = nn * 16 + (lane & 15);
                bf[nn] = *(const bf16x8*)&Bst[cur][row][(clog ^ (row & 7)) * 8];
            }
            #pragma unroll
            for (int m = 0; m < 2; ++m)
                #pragma unroll
                for (int nn = 0; nn < 4; ++nn)
                    acc[m][nn] = __builtin_amdgcn_mfma_f32_16x16x32_bf16(
                        af[m], bf[nn], acc[m][nn], 0, 0, 0);
        }
        __builtin_amdgcn_s_barrier();   // all reads of `cur` done before it's restaged
    }

    float rowdot[2][4] = {};
    #pragma unroll
    for (int nn = 0; nn < 4; ++nn) {
        int col = colbase + nn * 16 + (lane & 15);
        float bv = bias[col];
        float wv = FUSE ? Wout[col] : 0.f;
        #pragma unroll
        for (int m = 0; m < 2; ++m) {
            int grow0 = rowbase + wid * 32 + m * 16 + ((lane >> 4) << 2);
            f32x4 v = acc[m][nn];
            #pragma unroll
            for (int rr = 0; rr < 4; ++rr) {
                int row = grow0 + rr;
                if (row < n) {
                    float val = v[rr] + bv;
                    if (RELU) val = fmaxf(val, 0.f);
                    if (BF16OUT)
                        ((ushort*)Cout)[(size_t)row * 256 + col] = f2b(val);
                    else
                        ((float*)Cout)[(size_t)row * 256 + col] = val;
                    if (FUSE) rowdot[m][rr] = fmaf(val, wv, rowdot[m][rr]);
                }
            }
        }
    }
    if (FUSE) {
        #pragma unroll
        for (int m = 0; m < 2; ++m)
            #pragma unroll
            for (int rr = 0; rr < 4; ++rr) {
                float v = rowdot[m][rr];
                #pragma unroll
                for (int d = 1; d < 16; d <<= 1)
                    v += __shfl_xor(v, d, 64);   // reduce across 16 col-lanes
                if ((lane & 15) == 0) {
                    int row = rowbase + wid * 32 + m * 16 + ((lane >> 4) << 2) + rr;
                    if (row < n) atomicAdd(&outv[row], v);
                }
            }
    }
}

extern "C" void kernel_launch(void* const* d_in, const int* in_sizes, int n_in,
                              void* d_out, int out_size, void* d_ws, size_t ws_size,
                              hipStream_t stream) {
    const int n = NN, e = EE;
    const float* x    = (const float*)d_in[0];
    const int*   eidx = (const int*)d_in[1];
    const float* W1   = (const float*)d_in[2];
    const float* b1   = (const float*)d_in[3];
    const float* Wh   = (const float*)d_in[4];
    const float* bh   = (const float*)d_in[5];
    const float* W2   = (const float*)d_in[6];
    const float* b2   = (const float*)d_in[7];
    const float* Wout = (const float*)d_in[8];
    const float* bout = (const float*)d_in[9];
    const int* row = eidx;        // sources
    const int* col = eidx + e;    // destinations

    char* ws = (char*)d_ws;
    int*      cnt     = (int*)ws;      ws += (size_t)n * 4;
    int*      offs    = (int*)ws;      ws += (size_t)n * 4;
    int*      cursor  = (int*)ws;      ws += (size_t)n * 4;
    float*    dinv    = (float*)ws;    ws += (size_t)n * 4;
    int*      bsum    = (int*)ws;      ws += (size_t)256 * 4;
    unsigned* pq      = (unsigned*)ws; ws += (size_t)e * 4;
    ushort*   hb      = (ushort*)ws;   ws += (size_t)n * 256 * 2;   // bf16 hidden state
    ushort*   a2      = (ushort*)ws;   ws += (size_t)n * 512 * 2;   // A'' hi|lo [n][512]
    ushort*   wt      = (ushort*)ws;   ws += (size_t)3 * 256 * 768 * 2;
    ushort* wt1 = wt;
    ushort* wt2 = wt + (size_t)256 * 768;
    ushort* wt3 = wt + (size_t)2 * 256 * 768;

    float* outv = (float*)d_out;
    float* h3   = (float*)d_out + n;

    int nb_n = (n + 255) / 256;     // 79
    int nb_e = (e + 255) / 256;

    // CSR build
    init_cnt_kernel<<<nb_n, 256, 0, stream>>>(cnt, n);
    hist_kernel<<<nb_e, 256, 0, stream>>>(col, cnt, e);
    scan_p1_kernel<<<nb_n, 256, 0, stream>>>(cnt, offs, bsum, dinv, n);
    scan_p2_kernel<<<1, 256, 0, stream>>>(bsum, nb_n);
    scan_p3_kernel<<<nb_n, 256, 0, stream>>>(offs, bsum, cursor, n);
    scatter_kernel<<<nb_e, 256, 0, stream>>>(row, col, dinv, cursor, pq, e);

    // weight prep (1 launch) + x -> bf16 + out = bout
    wprep_kernel<<<dim3(256, 3), 256, 0, stream>>>(W1, Wh, W2, wt);
    cvt_kernel<<<(n * 32 + 255) / 256, 256, 0, stream>>>(x, hb, n * 32);
    init_out_kernel<<<nb_n, 256, 0, stream>>>(outv, bout, n);

    int agrid = (n / 8) * 4;            // 10000 blocks: chunk = bid&3, nodegroup = bid>>2
    dim3 ggrid((n + 127) / 128, 4);     // (157, 4) = 628 blocks

    // layer 1
    agg_kernel<<<agrid, 256, 0, stream>>>(hb, offs, cnt, pq, dinv, a2, n);
    gemm_mfma_kernel<true, true, false><<<ggrid, 256, 0, stream>>>(
        a2, wt1, b1, hb, nullptr, nullptr, n);
    // layer 2
    agg_kernel<<<agrid, 256, 0, stream>>>(hb, offs, cnt, pq, dinv, a2, n);
    gemm_mfma_kernel<true, true, false><<<ggrid, 256, 0, stream>>>(
        a2, wt2, bh, hb, nullptr, nullptr, n);
    // layer 3 -> h3 (f32) into d_out + fused decoder (out = h3 . Wout + bout)
    agg_kernel<<<agrid, 256, 0, stream>>>(hb, offs, cnt, pq, dinv, a2, n);
    gemm_mfma_kernel<false, false, true><<<ggrid, 256, 0, stream>>>(
        a2, wt3, b2, h3, Wout, outv, n);
}

// Round 14
// 223.125 us; speedup vs baseline: 1.8566x; 1.1470x over previous
//
#include <hip/hip_runtime.h>
#include <hip/hip_bf16.h>

#define NN 20000
#define EE 640000

typedef __attribute__((ext_vector_type(8))) short bf16x8;
typedef __attribute__((ext_vector_type(4))) float f32x4;

__device__ __forceinline__ ushort f2b(float f) {
    __hip_bfloat16 h = __float2bfloat16(f);
    return *(ushort*)&h;
}
__device__ __forceinline__ float b2f(ushort u) {
    __hip_bfloat16 h = *(__hip_bfloat16*)&u;
    return __bfloat162float(h);
}

// accumulate 8 bf16 feats (one 16B vector) scaled by m into acc[8]
__device__ __forceinline__ void acc8(float m, bf16x8 v, float* acc) {
    union { bf16x8 v; unsigned u[4]; } t;
    t.v = v;
    #pragma unroll
    for (int k = 0; k < 4; ++k) {
        acc[2 * k]     = fmaf(m, __uint_as_float(t.u[k] << 16), acc[2 * k]);
        acc[2 * k + 1] = fmaf(m, __uint_as_float(t.u[k] & 0xffff0000u), acc[2 * k + 1]);
    }
}

// async global->LDS, 16B per lane. LDS dest = wave-uniform base + lane*16.
__device__ __forceinline__ void gload16(const ushort* g, ushort* l) {
    __builtin_amdgcn_global_load_lds(
        (const __attribute__((address_space(1))) void*)g,
        (__attribute__((address_space(3))) void*)l, 16, 0, 0);
}

// ---------------- CSR build ----------------

__global__ void init_cnt_kernel(int* __restrict__ cnt, int n) {
    int i = blockIdx.x * 256 + threadIdx.x;
    if (i < n) cnt[i] = 0;
}

__global__ void hist_kernel(const int* __restrict__ col, int* __restrict__ cnt, int e) {
    int i = blockIdx.x * 256 + threadIdx.x;
    if (i < e) atomicAdd(&cnt[col[i]], 1);
}

__device__ __forceinline__ int block_exscan(int v) {
    __shared__ int wsum[4];
    int tid = threadIdx.x, lane = tid & 63, w = tid >> 6;
    int x = v;
    #pragma unroll
    for (int d = 1; d < 64; d <<= 1) {
        int y = __shfl_up(x, d, 64);
        if (lane >= d) x += y;
    }
    if (lane == 63) wsum[w] = x;
    __syncthreads();
    if (tid == 0) {
        int s = 0;
        #pragma unroll
        for (int k = 0; k < 4; ++k) { int t = wsum[k]; wsum[k] = s; s += t; }
    }
    __syncthreads();
    return wsum[w] + x - v;
}

// scan phase 1 + dinv fused
__global__ __launch_bounds__(256) void scan_p1_kernel(const int* __restrict__ cnt,
                                                      int* __restrict__ offs,
                                                      int* __restrict__ bsum,
                                                      float* __restrict__ dinv, int n) {
    int i = blockIdx.x * 256 + threadIdx.x;
    int v = (i < n) ? cnt[i] : 0;
    int e = block_exscan(v);
    if (i < n) {
        offs[i] = e;
        dinv[i] = rsqrtf((float)(v + 1));   // +1 self-loop; always > 0
    }
    if (threadIdx.x == 255) bsum[blockIdx.x] = e + v;
}

__global__ __launch_bounds__(256) void scan_p2_kernel(int* __restrict__ bsum, int nblk) {
    int t = threadIdx.x;
    int v = (t < nblk) ? bsum[t] : 0;
    int e = block_exscan(v);
    if (t < nblk) bsum[t] = e;
}

__global__ __launch_bounds__(256) void scan_p3_kernel(int* __restrict__ offs,
                                                      const int* __restrict__ bsum,
                                                      int* __restrict__ cursor, int n) {
    int i = blockIdx.x * 256 + threadIdx.x;
    if (i < n) {
        int o = offs[i] + bsum[blockIdx.x];
        offs[i] = o;
        cursor[i] = o;
    }
}

// pack: hi16 = bf16(norm), lo16 = src id (n < 65536)
__global__ void scatter_kernel(const int* __restrict__ row, const int* __restrict__ col,
                               const float* __restrict__ dinv, int* __restrict__ cursor,
                               unsigned* __restrict__ pq, int e) {
    int i = blockIdx.x * 256 + threadIdx.x;
    if (i >= e) return;
    int s = row[i], d = col[i];
    int pos = atomicAdd(&cursor[d], 1);
    unsigned nb = f2b(dinv[s] * dinv[d]);
    pq[pos] = (nb << 16) | (unsigned)s;
}

// ---------------- fused prep: 3x wprep (K=512 hi|lo) + x->bf16 + out=bout ----------------
__global__ __launch_bounds__(256) void prep_kernel(
    const float* __restrict__ W1, const float* __restrict__ Wh,
    const float* __restrict__ W2, ushort* __restrict__ Wt,
    const float* __restrict__ x, ushort* __restrict__ xb,
    const float* __restrict__ bout, float* __restrict__ outv, int n) {
    int bid = blockIdx.x;
    if (bid < 768) {
        const float* W = (bid < 256) ? W1 : ((bid < 512) ? Wh : W2);
        ushort* dst = Wt + (size_t)(bid >> 8) * 256 * 512;
        int col = bid & 255;
        #pragma unroll
        for (int kv = threadIdx.x; kv < 512; kv += 256) {
            int k = kv & 255;
            float w = W[(size_t)k * 256 + col];
            ushort hi = f2b(w);
            dst[(size_t)col * 512 + kv] = (kv < 256) ? hi : f2b(w - b2f(hi));
        }
    } else if (bid < 768 + 2500) {
        int i = (bid - 768) * 256 + threadIdx.x;   // per 8 elems, total n*32
        if (i < n * 32) {
            float4 a = ((const float4*)x)[2 * i];
            float4 b = ((const float4*)x)[2 * i + 1];
            union { bf16x8 v; ushort s[8]; } o;
            o.s[0] = f2b(a.x); o.s[1] = f2b(a.y); o.s[2] = f2b(a.z); o.s[3] = f2b(a.w);
            o.s[4] = f2b(b.x); o.s[5] = f2b(b.y); o.s[6] = f2b(b.z); o.s[7] = f2b(b.w);
            ((bf16x8*)xb)[i] = o.v;
        }
    } else {
        int i = (bid - 3268) * 256 + threadIdx.x;
        if (i < n) outv[i] = bout[0];
    }
}

// ---------------- bf16 MFMA GEMM: G = A @ W'' (pure matmul, bf16 out) ----------------
// A [n][256] bf16 (exact), virtual K=512: col = kv & 255 ([A|A] x [W_hi;W_lo]).
// 128x64 tile, LDS dbuf, counted vmcnt, XOR-swizzle both sides.
__global__ __launch_bounds__(256) void gemm_mfma_kernel(
    const ushort* __restrict__ A, const ushort* __restrict__ Wt,
    ushort* __restrict__ G, int n) {
    __shared__ ushort Ast[2][128][64];
    __shared__ ushort Bst[2][64][64];
    int tid = threadIdx.x;
    int lane = tid & 63, wid = tid >> 6;
    int rowbase = blockIdx.x * 128;
    int colbase = blockIdx.y * 64;

    f32x4 zero = {0.f, 0.f, 0.f, 0.f};
    f32x4 acc[2][4];
    #pragma unroll
    for (int m = 0; m < 2; ++m)
        #pragma unroll
        for (int nn = 0; nn < 4; ++nn) acc[m][nn] = zero;

    int rsub = lane >> 3, sl = lane & 7;
    const ushort* asrc[4];
    #pragma unroll
    for (int q = 0; q < 4; ++q) {
        int rin = wid * 32 + q * 8 + rsub;
        int c = sl ^ (rin & 7);
        int gr = min(rowbase + rin, n - 1);
        asrc[q] = A + (size_t)gr * 256 + c * 8;
    }
    const ushort* bsrc[2];
    #pragma unroll
    for (int q = 0; q < 2; ++q) {
        int rin = wid * 16 + q * 8 + rsub;
        int c = sl ^ (rin & 7);
        bsrc[q] = Wt + (size_t)(colbase + rin) * 512 + c * 8;
    }

    auto stage = [&](int kt, int buf) {
        int kv0 = kt * 64;
        int acol0 = kv0 & 255;
        #pragma unroll
        for (int q = 0; q < 4; ++q)
            gload16(asrc[q] + acol0, &Ast[buf][wid * 32 + q * 8][0]);
        #pragma unroll
        for (int q = 0; q < 2; ++q)
            gload16(bsrc[q] + kv0, &Bst[buf][wid * 16 + q * 8][0]);
    };

    stage(0, 0);
    for (int kt = 0; kt < 8; ++kt) {
        int cur = kt & 1;
        if (kt < 7) {
            stage(kt + 1, cur ^ 1);
            asm volatile("s_waitcnt vmcnt(6)" ::: "memory");
        } else {
            asm volatile("s_waitcnt vmcnt(0)" ::: "memory");
        }
        __builtin_amdgcn_s_barrier();
        #pragma unroll
        for (int kk = 0; kk < 2; ++kk) {
            int clog = kk * 4 + (lane >> 4);
            bf16x8 af[2], bf[4];
            #pragma unroll
            for (int m = 0; m < 2; ++m) {
                int row = wid * 32 + m * 16 + (lane & 15);
                af[m] = *(const bf16x8*)&Ast[cur][row][(clog ^ (row & 7)) * 8];
            }
            #pragma unroll
            for (int nn = 0; nn < 4; ++nn) {
                int row = nn * 16 + (lane & 15);
                bf[nn] = *(const bf16x8*)&Bst[cur][row][(clog ^ (row & 7)) * 8];
            }
            #pragma unroll
            for (int m = 0; m < 2; ++m)
                #pragma unroll
                for (int nn = 0; nn < 4; ++nn)
                    acc[m][nn] = __builtin_amdgcn_mfma_f32_16x16x32_bf16(
                        af[m], bf[nn], acc[m][nn], 0, 0, 0);
        }
        __builtin_amdgcn_s_barrier();
    }

    #pragma unroll
    for (int nn = 0; nn < 4; ++nn) {
        int col = colbase + nn * 16 + (lane & 15);
        #pragma unroll
        for (int m = 0; m < 2; ++m) {
            int grow0 = rowbase + wid * 32 + m * 16 + ((lane >> 4) << 2);
            f32x4 v = acc[m][nn];
            #pragma unroll
            for (int rr = 0; rr < 4; ++rr) {
                int row = grow0 + rr;
                if (row < n)
                    G[(size_t)row * 256 + col] = f2b(v[rr]);
            }
        }
    }
}

// ---------------- aggregation v11: h_out = [relu](Agg(G) + bias); optional fused decoder ----------------
// G bf16 [n][256]. chunk = bid&3 (slice 2.56MB, XCD-pinned). 4 waves x 2 nodes = 8 nodes/block.
// Lane: half = lane>>5, esub = (lane>>3)&3, fsub = lane&7. Meta pipelined 1 iter ahead.
template<bool FINAL>
__global__ __launch_bounds__(256) void agg_kernel(
    const ushort* __restrict__ g,
    const int* __restrict__ offs, const int* __restrict__ cnt,
    const unsigned* __restrict__ pq,
    const float* __restrict__ dinv,
    const float* __restrict__ bias,
    ushort* __restrict__ hb,          // !FINAL
    float* __restrict__ h3,           // FINAL
    const float* __restrict__ Wout, float* __restrict__ outv,
    int n) {
    int chunk = blockIdx.x & 3;
    int lane = threadIdx.x & 63;
    int half = lane >> 5;
    int esub = (lane >> 3) & 3;
    int fsub = lane & 7;
    int node = (blockIdx.x >> 2) * 8 + (threadIdx.x >> 6) * 2 + half;  // n%8==0
    const ushort* base = g + chunk * 64 + fsub * 8;

    int beg = offs[node], num = cnt[node];
    float acc[8] = {};

    unsigned q0 = pq[(esub)      < num ? beg + esub      : 0];
    unsigned q1 = pq[(4 + esub)  < num ? beg + 4 + esub  : 0];
    unsigned q2 = pq[(8 + esub)  < num ? beg + 8 + esub  : 0];
    unsigned q3 = pq[(12 + esub) < num ? beg + 12 + esub : 0];

    for (int j = 0; j < num; j += 16) {
        int jn = j + 16;
        unsigned p0 = pq[(jn + esub)      < num ? beg + jn + esub      : 0];
        unsigned p1 = pq[(jn + 4 + esub)  < num ? beg + jn + 4 + esub  : 0];
        unsigned p2 = pq[(jn + 8 + esub)  < num ? beg + jn + 8 + esub  : 0];
        unsigned p3 = pq[(jn + 12 + esub) < num ? beg + jn + 12 + esub : 0];

        float m0 = (j +      esub) < num ? __uint_as_float(q0 & 0xffff0000u) : 0.f;
        float m1 = (j + 4  + esub) < num ? __uint_as_float(q1 & 0xffff0000u) : 0.f;
        float m2 = (j + 8  + esub) < num ? __uint_as_float(q2 & 0xffff0000u) : 0.f;
        float m3 = (j + 12 + esub) < num ? __uint_as_float(q3 & 0xffff0000u) : 0.f;
        bf16x8 v0 = *(const bf16x8*)(base + (size_t)(q0 & 0xffffu) * 256);
        bf16x8 v1 = *(const bf16x8*)(base + (size_t)(q1 & 0xffffu) * 256);
        bf16x8 v2 = *(const bf16x8*)(base + (size_t)(q2 & 0xffffu) * 256);
        bf16x8 v3 = *(const bf16x8*)(base + (size_t)(q3 & 0xffffu) * 256);
        acc8(m0, v0, acc);
        acc8(m1, v1, acc);
        acc8(m2, v2, acc);
        acc8(m3, v3, acc);
        q0 = p0; q1 = p1; q2 = p2; q3 = p3;
    }

    // reduce across the 4 esub groups within each 32-lane half
    #pragma unroll
    for (int d = 8; d < 32; d <<= 1)
        #pragma unroll
        for (int k = 0; k < 8; ++k)
            acc[k] += __shfl_xor(acc[k], d, 64);

    if (esub == 0) {   // lanes 0-7 (node A) and 32-39 (node B) hold fsub 0..7
        float di = dinv[node];
        bf16x8 sv = *(const bf16x8*)(base + (size_t)node * 256);
        acc8(di * di, sv, acc);
        int feat = chunk * 64 + fsub * 8;
        float4 b0 = *(const float4*)(bias + feat);
        float4 b1 = *(const float4*)(bias + feat + 4);
        acc[0] += b0.x; acc[1] += b0.y; acc[2] += b0.z; acc[3] += b0.w;
        acc[4] += b1.x; acc[5] += b1.y; acc[6] += b1.z; acc[7] += b1.w;
        if (!FINAL) {
            union { bf16x8 v; ushort s[8]; } o;
            #pragma unroll
            for (int k = 0; k < 8; ++k)
                o.s[k] = f2b(fmaxf(acc[k], 0.f));
            *(bf16x8*)(hb + (size_t)node * 256 + feat) = o.v;
        } else {
            float4 o0 = {acc[0], acc[1], acc[2], acc[3]};
            float4 o1 = {acc[4], acc[5], acc[6], acc[7]};
            *(float4*)(h3 + (size_t)node * 256 + feat)     = o0;
            *(float4*)(h3 + (size_t)node * 256 + feat + 4) = o1;
            float4 w0 = *(const float4*)(Wout + feat);
            float4 w1 = *(const float4*)(Wout + feat + 4);
            float dot = acc[0] * w0.x + acc[1] * w0.y + acc[2] * w0.z + acc[3] * w0.w
                      + acc[4] * w1.x + acc[5] * w1.y + acc[6] * w1.z + acc[7] * w1.w;
            #pragma unroll
            for (int d = 1; d < 8; d <<= 1)
                dot += __shfl_xor(dot, d, 64);   // reduce across 8 fsub lanes
            if (fsub == 0) atomicAdd(&outv[node], dot);
        }
    }
}

extern "C" void kernel_launch(void* const* d_in, const int* in_sizes, int n_in,
                              void* d_out, int out_size, void* d_ws, size_t ws_size,
                              hipStream_t stream) {
    const int n = NN, e = EE;
    const float* x    = (const float*)d_in[0];
    const int*   eidx = (const int*)d_in[1];
    const float* W1   = (const float*)d_in[2];
    const float* b1   = (const float*)d_in[3];
    const float* Wh   = (const float*)d_in[4];
    const float* bh   = (const float*)d_in[5];
    const float* W2   = (const float*)d_in[6];
    const float* b2   = (const float*)d_in[7];
    const float* Wout = (const float*)d_in[8];
    const float* bout = (const float*)d_in[9];
    const int* row = eidx;        // sources
    const int* col = eidx + e;    // destinations

    char* ws = (char*)d_ws;
    int*      cnt     = (int*)ws;      ws += (size_t)n * 4;
    int*      offs    = (int*)ws;      ws += (size_t)n * 4;
    int*      cursor  = (int*)ws;      ws += (size_t)n * 4;
    float*    dinv    = (float*)ws;    ws += (size_t)n * 4;
    int*      bsum    = (int*)ws;      ws += (size_t)256 * 4;
    unsigned* pq      = (unsigned*)ws; ws += (size_t)e * 4;
    ushort*   xb      = (ushort*)ws;   ws += (size_t)n * 256 * 2;   // bf16 x
    ushort*   hb      = (ushort*)ws;   ws += (size_t)n * 256 * 2;   // bf16 hidden
    ushort*   g2      = (ushort*)ws;   ws += (size_t)n * 256 * 2;   // bf16 GEMM out
    ushort*   wt      = (ushort*)ws;   ws += (size_t)3 * 256 * 512 * 2;
    ushort* wt1 = wt;
    ushort* wt2 = wt + (size_t)256 * 512;
    ushort* wt3 = wt + (size_t)2 * 256 * 512;

    float* outv = (float*)d_out;
    float* h3   = (float*)d_out + n;

    int nb_n = (n + 255) / 256;     // 79
    int nb_e = (e + 255) / 256;

    // CSR build
    init_cnt_kernel<<<nb_n, 256, 0, stream>>>(cnt, n);
    hist_kernel<<<nb_e, 256, 0, stream>>>(col, cnt, e);
    scan_p1_kernel<<<nb_n, 256, 0, stream>>>(cnt, offs, bsum, dinv, n);
    scan_p2_kernel<<<1, 256, 0, stream>>>(bsum, nb_n);
    scan_p3_kernel<<<nb_n, 256, 0, stream>>>(offs, bsum, cursor, n);
    scatter_kernel<<<nb_e, 256, 0, stream>>>(row, col, dinv, cursor, pq, e);

    // fused prep: wprep x3 + cvt + init_out
    prep_kernel<<<768 + 2500 + 79, 256, 0, stream>>>(W1, Wh, W2, wt, x, xb, bout, outv, n);

    int agrid = (n / 8) * 4;            // 10000 blocks
    dim3 ggrid((n + 127) / 128, 4);     // (157, 4) = 628 blocks

    // layer 1: G1 = xb @ W1'' ; hb = relu(Agg(G1) + b1)
    gemm_mfma_kernel<<<ggrid, 256, 0, stream>>>(xb, wt1, g2, n);
    agg_kernel<false><<<agrid, 256, 0, stream>>>(
        g2, offs, cnt, pq, dinv, b1, hb, nullptr, nullptr, nullptr, n);
    // layer 2
    gemm_mfma_kernel<<<ggrid, 256, 0, stream>>>(hb, wt2, g2, n);
    agg_kernel<false><<<agrid, 256, 0, stream>>>(
        g2, offs, cnt, pq, dinv, bh, hb, nullptr, nullptr, nullptr, n);
    // layer 3: G3 = hb @ W2'' ; h3 = Agg(G3) + b2 (f32, into d_out) + fused decoder
    gemm_mfma_kernel<<<ggrid, 256, 0, stream>>>(hb, wt3, g2, n);
    agg_kernel<true><<<agrid, 256, 0, stream>>>(
        g2, offs, cnt, pq, dinv, b2, nullptr, h3, Wout, outv, n);
}